// Round 2
// baseline (5127.250 us; speedup 1.0000x reference)
//
#include <hip/hip_runtime.h>

// NGCF forward, MI355X. Sizes fixed by the problem.
constexpr int N_NODES = 300000;   // N_USERS + N_ITEMS
constexpr int DIM = 64;

// ---------------------------------------------------------------------------
// SpMM: side[rows[e]][d] += vals[e] * ego[cols[e]][d]
// One thread per (edge, dim). 64 consecutive threads = one edge = one wave,
// so the gather ego[c*64+d] is a fully coalesced 256B read and rows/cols/vals
// loads are wave-uniform (broadcast).
// ---------------------------------------------------------------------------
__global__ __launch_bounds__(256) void spmm_atomic_kernel(
    const float* __restrict__ ego,
    const int*   __restrict__ rows,
    const int*   __restrict__ cols,
    const float* __restrict__ vals,
    float*       __restrict__ side,
    int nnz)
{
    long long i = (long long)blockIdx.x * blockDim.x + threadIdx.x;
    long long total = (long long)nnz * DIM;
    if (i >= total) return;
    int e = (int)(i >> 6);
    int d = (int)(i & 63);
    int r = rows[e];
    int c = cols[e];
    float v = vals[e];
    atomicAdd(side + ((size_t)r * DIM + d), v * ego[(size_t)c * DIM + d]);
}

// ---------------------------------------------------------------------------
// Dense part of one NGCF layer, one wave per node, lane = output dim o:
//   s = side + ego ; p = ego * side
//   y = leaky_relu(s @ gw.T + gb + p @ bw.T + bb, 0.2)
//   ego_out = y ; out[n*192 + out_col + o] = y / max(||y||, 1e-12)
// Weights are staged TRANSPOSED in LDS: w_t[k][o] = w[o][k], so
// acc += s[k] * w_t[k][o] == (s @ w.T)[o]. Lane reads are consecutive.
// ---------------------------------------------------------------------------
__global__ __launch_bounds__(256) void dense_norm_kernel(
    const float* __restrict__ ego_in,
    const float* __restrict__ side,
    const float* __restrict__ gw,
    const float* __restrict__ gb,
    const float* __restrict__ bw,
    const float* __restrict__ bb,
    float*       __restrict__ ego_out,
    float*       __restrict__ out,
    int out_col)
{
    __shared__ float w_t[2][DIM * DIM];
    for (int i = threadIdx.x; i < DIM * DIM; i += 256) {
        int r = i >> 6, c = i & 63;        // gw_flat[i] = gw[r][c]
        w_t[0][c * DIM + r] = gw[i];       // w_t[c][r] = gw[r][c]  (transpose)
        w_t[1][c * DIM + r] = bw[i];
    }
    __syncthreads();

    const int local = threadIdx.x >> 6;   // wave id in block (0..3)
    const int o     = threadIdx.x & 63;   // output dim owned by this lane
    const float bias = gb[o] + bb[o];

    for (int n = blockIdx.x * 4 + local; n < N_NODES; n += gridDim.x * 4) {
        float e = ego_in[(size_t)n * DIM + o];
        float s = side[(size_t)n * DIM + o];
        float sv = s + e;      // dim o of (side + ego)
        float pv = s * e;      // dim o of (side * ego)

        float acc = bias;
#pragma unroll
        for (int k = 0; k < DIM; ++k) {
            float sk = __shfl(sv, k);
            float pk = __shfl(pv, k);
            acc += sk * w_t[0][k * DIM + o] + pk * w_t[1][k * DIM + o];
        }
        float y = acc > 0.0f ? acc : 0.2f * acc;   // leaky_relu(0.2)

        ego_out[(size_t)n * DIM + o] = y;

        // row L2 norm across the 64 lanes
        float ss = y * y;
#pragma unroll
        for (int off = 32; off > 0; off >>= 1)
            ss += __shfl_xor(ss, off);
        float inv = 1.0f / fmaxf(sqrtf(ss), 1e-12f);

        out[(size_t)n * 192 + out_col + o] = y * inv;
    }
}

// out[:, 0:64] = emb, vectorized float4 copy
__global__ __launch_bounds__(256) void copy_emb_kernel(
    const float4* __restrict__ emb, float4* __restrict__ out)
{
    int i = blockIdx.x * blockDim.x + threadIdx.x;   // N_NODES*16 float4s
    if (i >= N_NODES * 16) return;
    int n = i >> 4, j = i & 15;
    out[(size_t)n * 48 + j] = emb[i];
}

extern "C" void kernel_launch(void* const* d_in, const int* in_sizes, int n_in,
                              void* d_out, int out_size, void* d_ws, size_t ws_size,
                              hipStream_t stream)
{
    const float* emb   = (const float*)d_in[0];
    const float* gc_w0 = (const float*)d_in[1];
    const float* gc_b0 = (const float*)d_in[2];
    const float* bi_w0 = (const float*)d_in[3];
    const float* bi_b0 = (const float*)d_in[4];
    const float* gc_w1 = (const float*)d_in[5];
    const float* gc_b1 = (const float*)d_in[6];
    const float* bi_w1 = (const float*)d_in[7];
    const float* bi_b1 = (const float*)d_in[8];
    const int*   rows  = (const int*)d_in[9];
    const int*   cols  = (const int*)d_in[10];
    const float* vals  = (const float*)d_in[11];
    const int    nnz   = in_sizes[9];

    float* out  = (float*)d_out;
    float* side = (float*)d_ws;                         // [N_NODES, 64]
    float* ego1 = side + (size_t)N_NODES * DIM;         // [N_NODES, 64]

    const size_t side_bytes = (size_t)N_NODES * DIM * sizeof(float);
    const long long total = (long long)nnz * DIM;
    const int spmm_blocks = (int)((total + 255) / 256);

    // ---- layer 0 ----
    hipMemsetAsync(side, 0, side_bytes, stream);
    spmm_atomic_kernel<<<spmm_blocks, 256, 0, stream>>>(emb, rows, cols, vals, side, nnz);
    dense_norm_kernel<<<2048, 256, 0, stream>>>(emb, side, gc_w0, gc_b0, bi_w0, bi_b0,
                                                ego1, out, DIM);

    // ---- layer 1 ---- (ego_out written in-place over ego1; safe: each wave
    // reads only its own node's row before writing it)
    hipMemsetAsync(side, 0, side_bytes, stream);
    spmm_atomic_kernel<<<spmm_blocks, 256, 0, stream>>>(ego1, rows, cols, vals, side, nnz);
    dense_norm_kernel<<<2048, 256, 0, stream>>>(ego1, side, gc_w1, gc_b1, bi_w1, bi_b1,
                                                ego1, out, 2 * DIM);

    // ---- out[:, 0:64] = emb ----
    copy_emb_kernel<<<(N_NODES * 16 + 255) / 256, 256, 0, stream>>>(
        (const float4*)emb, (float4*)out);
}

// Round 3
// 2707.196 us; speedup vs baseline: 1.8939x; 1.8939x over previous
//
#include <hip/hip_runtime.h>

// NGCF forward, MI355X. Sizes fixed by the problem.
constexpr int N_NODES = 300000;   // N_USERS + N_ITEMS
constexpr int DIM = 64;
constexpr int SCAN_B = 2048;      // elements scanned per block in scan1

// ---------------------------------------------------------------------------
// CSR build: histogram -> exclusive scan -> scatter
// ---------------------------------------------------------------------------
__global__ __launch_bounds__(256) void hist_kernel(
    const int* __restrict__ rows, int* __restrict__ counts, int nnz)
{
    int e = blockIdx.x * 256 + threadIdx.x;
    if (e < nnz) atomicAdd(&counts[rows[e]], 1);
}

// Per-block scan of SCAN_B elements (8/thread), writes local exclusive prefix
// and per-block total.
__global__ __launch_bounds__(256) void scan1_kernel(
    const int* __restrict__ c, int* __restrict__ ps, int* __restrict__ bsum, int n)
{
    __shared__ int tsum[256];
    int base = blockIdx.x * SCAN_B;
    int v[8];
    int s = 0;
#pragma unroll
    for (int k = 0; k < 8; ++k) {
        int i = base + threadIdx.x * 8 + k;
        v[k] = (i < n) ? c[i] : 0;
        s += v[k];
    }
    tsum[threadIdx.x] = s;
    __syncthreads();
    for (int off = 1; off < 256; off <<= 1) {
        int u = (threadIdx.x >= off) ? tsum[threadIdx.x - off] : 0;
        __syncthreads();
        tsum[threadIdx.x] += u;
        __syncthreads();
    }
    int excl = (threadIdx.x == 0) ? 0 : tsum[threadIdx.x - 1];
#pragma unroll
    for (int k = 0; k < 8; ++k) {
        int i = base + threadIdx.x * 8 + k;
        if (i < n) ps[i] = excl;
        excl += v[k];
    }
    if (threadIdx.x == 255) bsum[blockIdx.x] = tsum[255];
}

// Single-block exclusive scan of the (<=256) block sums.
__global__ __launch_bounds__(256) void scan2_kernel(int* bsum, int nb)
{
    __shared__ int t[256];
    int v = (threadIdx.x < nb) ? bsum[threadIdx.x] : 0;
    t[threadIdx.x] = v;
    __syncthreads();
    for (int off = 1; off < 256; off <<= 1) {
        int u = (threadIdx.x >= off) ? t[threadIdx.x - off] : 0;
        __syncthreads();
        t[threadIdx.x] += u;
        __syncthreads();
    }
    if (threadIdx.x < nb) bsum[threadIdx.x] = t[threadIdx.x] - v;
}

// Add block offsets; also init the scatter cursor and row_ptr[n].
__global__ __launch_bounds__(256) void scan3_kernel(
    int* __restrict__ ps, int* __restrict__ fill,
    const int* __restrict__ bsum, int n, int nnz)
{
    int i = blockIdx.x * 256 + threadIdx.x;
    if (i == 0) ps[n] = nnz;
    if (i < n) {
        int v = ps[i] + bsum[i / SCAN_B];
        ps[i] = v;
        fill[i] = v;
    }
}

__global__ __launch_bounds__(256) void scatter_kernel(
    const int* __restrict__ rows, const int* __restrict__ cols,
    const float* __restrict__ vals, int* __restrict__ fill,
    int* __restrict__ cols_s, float* __restrict__ vals_s, int nnz)
{
    int e = blockIdx.x * 256 + threadIdx.x;
    if (e >= nnz) return;
    int p = atomicAdd(&fill[rows[e]], 1);
    cols_s[p] = cols[e];
    vals_s[p] = vals[e];
}

// ---------------------------------------------------------------------------
// CSR SpMM: one wave per row. Lanes split 4 edge-slots x 16 dim-quarters;
// each iteration gathers 4 edges (1 KB in flight), accumulate in float4 regs,
// cross-slot reduce at the end, one 256B store per row. No atomics.
// ---------------------------------------------------------------------------
__global__ __launch_bounds__(256) void spmm_csr_kernel(
    const float4* __restrict__ ego,     // [N_NODES*16] float4 view
    const int*    __restrict__ row_ptr,
    const int*    __restrict__ cols_s,
    const float*  __restrict__ vals_s,
    float4*       __restrict__ side)    // [N_NODES*16] float4 view
{
    int wid  = (blockIdx.x * 256 + threadIdx.x) >> 6;   // row
    if (wid >= N_NODES) return;
    int lane = threadIdx.x & 63;
    int g    = lane >> 4;        // edge slot 0..3
    int q    = lane & 15;        // dim quarter

    int start = row_ptr[wid];
    int end   = row_ptr[wid + 1];

    float4 acc = {0.f, 0.f, 0.f, 0.f};
    for (int j = start + g; j < end; j += 4) {
        int   c = cols_s[j];
        float v = vals_s[j];
        float4 x = ego[(size_t)c * 16 + q];
        acc.x += v * x.x; acc.y += v * x.y; acc.z += v * x.z; acc.w += v * x.w;
    }
    // reduce across the 4 edge slots (lane bits 4 and 5)
#pragma unroll
    for (int off = 16; off <= 32; off <<= 1) {
        acc.x += __shfl_xor(acc.x, off);
        acc.y += __shfl_xor(acc.y, off);
        acc.z += __shfl_xor(acc.z, off);
        acc.w += __shfl_xor(acc.w, off);
    }
    if (g == 0) side[(size_t)wid * 16 + q] = acc;
}

// ---------------------------------------------------------------------------
// Fallback SpMM (atomic, edge-parallel) if ws is too small for CSR.
// ---------------------------------------------------------------------------
__global__ __launch_bounds__(256) void spmm_atomic_kernel(
    const float* __restrict__ ego,
    const int*   __restrict__ rows,
    const int*   __restrict__ cols,
    const float* __restrict__ vals,
    float*       __restrict__ side,
    int nnz)
{
    long long i = (long long)blockIdx.x * blockDim.x + threadIdx.x;
    long long total = (long long)nnz * DIM;
    if (i >= total) return;
    int e = (int)(i >> 6);
    int d = (int)(i & 63);
    atomicAdd(side + ((size_t)rows[e] * DIM + d), vals[e] * ego[(size_t)cols[e] * DIM + d]);
}

// ---------------------------------------------------------------------------
// Dense part of one NGCF layer, one wave per node, lane = output dim o.
// Weights staged TRANSPOSED in LDS: w_t[k][o] = w[o][k].
// ---------------------------------------------------------------------------
__global__ __launch_bounds__(256) void dense_norm_kernel(
    const float* __restrict__ ego_in,
    const float* __restrict__ side,
    const float* __restrict__ gw,
    const float* __restrict__ gb,
    const float* __restrict__ bw,
    const float* __restrict__ bb,
    float*       __restrict__ ego_out,
    float*       __restrict__ out,
    int out_col)
{
    __shared__ float w_t[2][DIM * DIM];
    for (int i = threadIdx.x; i < DIM * DIM; i += 256) {
        int r = i >> 6, c = i & 63;        // gw_flat[i] = gw[r][c]
        w_t[0][c * DIM + r] = gw[i];       // transpose
        w_t[1][c * DIM + r] = bw[i];
    }
    __syncthreads();

    const int local = threadIdx.x >> 6;
    const int o     = threadIdx.x & 63;
    const float bias = gb[o] + bb[o];

    for (int n = blockIdx.x * 4 + local; n < N_NODES; n += gridDim.x * 4) {
        float e = ego_in[(size_t)n * DIM + o];
        float s = side[(size_t)n * DIM + o];
        float sv = s + e;
        float pv = s * e;

        float acc = bias;
#pragma unroll
        for (int k = 0; k < DIM; ++k) {
            float sk = __shfl(sv, k);
            float pk = __shfl(pv, k);
            acc += sk * w_t[0][k * DIM + o] + pk * w_t[1][k * DIM + o];
        }
        float y = acc > 0.0f ? acc : 0.2f * acc;

        ego_out[(size_t)n * DIM + o] = y;

        float ss = y * y;
#pragma unroll
        for (int off = 32; off > 0; off >>= 1)
            ss += __shfl_xor(ss, off);
        float inv = 1.0f / fmaxf(sqrtf(ss), 1e-12f);

        out[(size_t)n * 192 + out_col + o] = y * inv;
    }
}

// out[:, 0:64] = emb
__global__ __launch_bounds__(256) void copy_emb_kernel(
    const float4* __restrict__ emb, float4* __restrict__ out)
{
    int i = blockIdx.x * blockDim.x + threadIdx.x;
    if (i >= N_NODES * 16) return;
    int n = i >> 4, j = i & 15;
    out[(size_t)n * 48 + j] = emb[i];
}

extern "C" void kernel_launch(void* const* d_in, const int* in_sizes, int n_in,
                              void* d_out, int out_size, void* d_ws, size_t ws_size,
                              hipStream_t stream)
{
    const float* emb   = (const float*)d_in[0];
    const float* gc_w0 = (const float*)d_in[1];
    const float* gc_b0 = (const float*)d_in[2];
    const float* bi_w0 = (const float*)d_in[3];
    const float* bi_b0 = (const float*)d_in[4];
    const float* gc_w1 = (const float*)d_in[5];
    const float* gc_b1 = (const float*)d_in[6];
    const float* bi_w1 = (const float*)d_in[7];
    const float* bi_b1 = (const float*)d_in[8];
    const int*   rows  = (const int*)d_in[9];
    const int*   cols  = (const int*)d_in[10];
    const float* vals  = (const float*)d_in[11];
    const int    nnz   = in_sizes[9];

    float* out = (float*)d_out;

    // ---- workspace layout ----
    char* ws = (char*)d_ws;
    size_t off = 0;
    auto alloc = [&](size_t bytes) { char* p = ws + off; off += (bytes + 15) & ~size_t(15); return p; };
    float* side    = (float*)alloc((size_t)N_NODES * DIM * sizeof(float));
    float* ego1    = (float*)alloc((size_t)N_NODES * DIM * sizeof(float));
    int*   cols_s  = (int*)  alloc((size_t)nnz * sizeof(int));
    float* vals_s  = (float*)alloc((size_t)nnz * sizeof(float));
    int*   counts  = (int*)  alloc((size_t)N_NODES * sizeof(int));
    int*   row_ptr = (int*)  alloc((size_t)(N_NODES + 1) * sizeof(int));
    int*   fill    = (int*)  alloc((size_t)N_NODES * sizeof(int));
    int*   bsum    = (int*)  alloc(1024 * sizeof(int));
    const bool csr_ok = off <= ws_size;

    const int eb   = (nnz + 255) / 256;                   // edge-parallel blocks
    const int nb_s = (N_NODES + SCAN_B - 1) / SCAN_B;     // scan1 blocks (147)
    const int nbN  = (N_NODES + 255) / 256;
    const int spmm_blocks = (N_NODES * 64 + 255) / 256;   // wave per row

    if (csr_ok) {
        // ---- CSR build (shared by both layers) ----
        hipMemsetAsync(counts, 0, (size_t)N_NODES * sizeof(int), stream);
        hist_kernel<<<eb, 256, 0, stream>>>(rows, counts, nnz);
        scan1_kernel<<<nb_s, 256, 0, stream>>>(counts, row_ptr, bsum, N_NODES);
        scan2_kernel<<<1, 256, 0, stream>>>(bsum, nb_s);
        scan3_kernel<<<nbN, 256, 0, stream>>>(row_ptr, fill, bsum, N_NODES, nnz);
        scatter_kernel<<<eb, 256, 0, stream>>>(rows, cols, vals, fill, cols_s, vals_s, nnz);

        // ---- layer 0 ----
        spmm_csr_kernel<<<spmm_blocks, 256, 0, stream>>>(
            (const float4*)emb, row_ptr, cols_s, vals_s, (float4*)side);
        dense_norm_kernel<<<2048, 256, 0, stream>>>(emb, side, gc_w0, gc_b0, bi_w0, bi_b0,
                                                    ego1, out, DIM);
        // ---- layer 1 ----
        spmm_csr_kernel<<<spmm_blocks, 256, 0, stream>>>(
            (const float4*)ego1, row_ptr, cols_s, vals_s, (float4*)side);
        dense_norm_kernel<<<2048, 256, 0, stream>>>(ego1, side, gc_w1, gc_b1, bi_w1, bi_b1,
                                                    ego1, out, 2 * DIM);
    } else {
        // ---- fallback: atomic SpMM ----
        const size_t side_bytes = (size_t)N_NODES * DIM * sizeof(float);
        const long long total = (long long)nnz * DIM;
        const int ab = (int)((total + 255) / 256);
        hipMemsetAsync(side, 0, side_bytes, stream);
        spmm_atomic_kernel<<<ab, 256, 0, stream>>>(emb, rows, cols, vals, side, nnz);
        dense_norm_kernel<<<2048, 256, 0, stream>>>(emb, side, gc_w0, gc_b0, bi_w0, bi_b0,
                                                    ego1, out, DIM);
        hipMemsetAsync(side, 0, side_bytes, stream);
        spmm_atomic_kernel<<<ab, 256, 0, stream>>>(ego1, rows, cols, vals, side, nnz);
        dense_norm_kernel<<<2048, 256, 0, stream>>>(ego1, side, gc_w1, gc_b1, bi_w1, bi_b1,
                                                    ego1, out, 2 * DIM);
    }

    copy_emb_kernel<<<(N_NODES * 16 + 255) / 256, 256, 0, stream>>>(
        (const float4*)emb, (float4*)out);
}

// Round 4
// 1957.755 us; speedup vs baseline: 2.6189x; 1.3828x over previous
//
#include <hip/hip_runtime.h>

// NGCF forward, MI355X. Sizes fixed by the problem.
constexpr int N_NODES = 300000;   // N_USERS + N_ITEMS
constexpr int DIM = 64;
constexpr int SCAN_B = 2048;

typedef unsigned short ushort_t;

__device__ __forceinline__ float blo(unsigned u) { return __uint_as_float(u << 16); }
__device__ __forceinline__ float bhi(unsigned u) { return __uint_as_float(u & 0xffff0000u); }
__device__ __forceinline__ ushort_t f2b(float f) {            // fp32 -> bf16 (RNE)
    unsigned u = __float_as_uint(f);
    return (ushort_t)((u + 0x7fffu + ((u >> 16) & 1u)) >> 16);
}

// ---------------------------------------------------------------------------
// CSR build: histogram -> exclusive scan -> scatter (packed int2 payload)
// ---------------------------------------------------------------------------
__global__ __launch_bounds__(256) void hist_kernel(
    const int* __restrict__ rows, int* __restrict__ counts, int nnz)
{
    int e = blockIdx.x * 256 + threadIdx.x;
    if (e < nnz) atomicAdd(&counts[rows[e]], 1);
}

__global__ __launch_bounds__(256) void scan1_kernel(
    const int* __restrict__ c, int* __restrict__ ps, int* __restrict__ bsum, int n)
{
    __shared__ int tsum[256];
    int base = blockIdx.x * SCAN_B;
    int v[8];
    int s = 0;
#pragma unroll
    for (int k = 0; k < 8; ++k) {
        int i = base + threadIdx.x * 8 + k;
        v[k] = (i < n) ? c[i] : 0;
        s += v[k];
    }
    tsum[threadIdx.x] = s;
    __syncthreads();
    for (int off = 1; off < 256; off <<= 1) {
        int u = (threadIdx.x >= off) ? tsum[threadIdx.x - off] : 0;
        __syncthreads();
        tsum[threadIdx.x] += u;
        __syncthreads();
    }
    int excl = (threadIdx.x == 0) ? 0 : tsum[threadIdx.x - 1];
#pragma unroll
    for (int k = 0; k < 8; ++k) {
        int i = base + threadIdx.x * 8 + k;
        if (i < n) ps[i] = excl;
        excl += v[k];
    }
    if (threadIdx.x == 255) bsum[blockIdx.x] = tsum[255];
}

__global__ __launch_bounds__(256) void scan2_kernel(int* bsum, int nb)
{
    __shared__ int t[256];
    int v = (threadIdx.x < nb) ? bsum[threadIdx.x] : 0;
    t[threadIdx.x] = v;
    __syncthreads();
    for (int off = 1; off < 256; off <<= 1) {
        int u = (threadIdx.x >= off) ? t[threadIdx.x - off] : 0;
        __syncthreads();
        t[threadIdx.x] += u;
        __syncthreads();
    }
    if (threadIdx.x < nb) bsum[threadIdx.x] = t[threadIdx.x] - v;
}

__global__ __launch_bounds__(256) void scan3_kernel(
    int* __restrict__ ps, int* __restrict__ fill,
    const int* __restrict__ bsum, int n, int nnz)
{
    int i = blockIdx.x * 256 + threadIdx.x;
    if (i == 0) ps[n] = nnz;
    if (i < n) {
        int v = ps[i] + bsum[i / SCAN_B];
        ps[i] = v;
        fill[i] = v;
    }
}

__global__ __launch_bounds__(256) void scatter_kernel(
    const int* __restrict__ rows, const int* __restrict__ cols,
    const float* __restrict__ vals, int* __restrict__ fill,
    int2* __restrict__ meta, int nnz)
{
    int e = blockIdx.x * 256 + threadIdx.x;
    if (e >= nnz) return;
    int p = atomicAdd(&fill[rows[e]], 1);
    meta[p] = make_int2(cols[e], __float_as_int(vals[e]));   // one 8B store
}

// fp32 [N,64] -> bf16 table [N,64] (ushort)
__global__ __launch_bounds__(256) void convert_bf16_kernel(
    const float4* __restrict__ src, ushort4* __restrict__ dst, int n4)
{
    int i = blockIdx.x * 256 + threadIdx.x;
    if (i >= n4) return;
    float4 x = src[i];
    ushort4 u;
    u.x = f2b(x.x); u.y = f2b(x.y); u.z = f2b(x.z); u.w = f2b(x.w);
    dst[i] = u;
}

// ---------------------------------------------------------------------------
// CSR SpMM with bf16 gather table: one wave per row.
// 8 edge slots (g) x 8 dim-eighths (q, 16B = 8 bf16 each). Per iteration the
// wave gathers 8 edges x 128B; fp32 accumulate; 3-round cross-slot reduce;
// one 256B row store. No atomics.
// ---------------------------------------------------------------------------
__global__ __launch_bounds__(256) void spmm_csr_b_kernel(
    const uint4* __restrict__ ego_b,    // [N_NODES*8] rows of 64 bf16
    const int*   __restrict__ row_ptr,
    const int2*  __restrict__ meta,     // packed (col, val_bits)
    float*       __restrict__ side)     // fp32 [N_NODES,64]
{
    int wid = (blockIdx.x * 256 + threadIdx.x) >> 6;
    if (wid >= N_NODES) return;
    int lane = threadIdx.x & 63;
    int g = lane >> 3;       // edge slot 0..7
    int q = lane & 7;        // dim eighth

    int start = row_ptr[wid];
    int end   = row_ptr[wid + 1];

    float acc[8];
#pragma unroll
    for (int i = 0; i < 8; ++i) acc[i] = 0.f;

    for (int j = start + g; j < end; j += 8) {
        int2 m = meta[j];
        float v = __int_as_float(m.y);
        uint4 x = ego_b[(size_t)m.x * 8 + q];
        acc[0] += v * blo(x.x); acc[1] += v * bhi(x.x);
        acc[2] += v * blo(x.y); acc[3] += v * bhi(x.y);
        acc[4] += v * blo(x.z); acc[5] += v * bhi(x.z);
        acc[6] += v * blo(x.w); acc[7] += v * bhi(x.w);
    }
#pragma unroll
    for (int off = 8; off <= 32; off <<= 1) {
#pragma unroll
        for (int i = 0; i < 8; ++i) acc[i] += __shfl_xor(acc[i], off);
    }
    if (g == 0) {
        float4* dst = (float4*)(side + (size_t)wid * DIM + q * 8);
        dst[0] = make_float4(acc[0], acc[1], acc[2], acc[3]);
        dst[1] = make_float4(acc[4], acc[5], acc[6], acc[7]);
    }
}

// Fallback SpMM (atomic, edge-parallel) if ws is too small for CSR.
__global__ __launch_bounds__(256) void spmm_atomic_kernel(
    const float* __restrict__ ego,
    const int*   __restrict__ rows,
    const int*   __restrict__ cols,
    const float* __restrict__ vals,
    float*       __restrict__ side,
    int nnz)
{
    long long i = (long long)blockIdx.x * blockDim.x + threadIdx.x;
    long long total = (long long)nnz * DIM;
    if (i >= total) return;
    int e = (int)(i >> 6);
    int d = (int)(i & 63);
    atomicAdd(side + ((size_t)rows[e] * DIM + d), vals[e] * ego[(size_t)cols[e] * DIM + d]);
}

// ---------------------------------------------------------------------------
// Dense part of one NGCF layer. 32 nodes staged per block (s=side+ego,
// p=side*ego in LDS); weights live in per-lane registers (lane o holds
// gw[o][:], bw[o][:]); inner loop = float4 LDS broadcasts + FMA, 4 acc chains.
// ---------------------------------------------------------------------------
template<bool EGO_B16, bool WRITE_F32, bool WRITE_B16>
__global__ __launch_bounds__(256) void dense_norm_kernel(
    const float*   __restrict__ ego_f32,   // used if !EGO_B16
    const ushort_t* __restrict__ ego_b16,  // used if EGO_B16
    const float* __restrict__ side,
    const float* __restrict__ gw, const float* __restrict__ gb,
    const float* __restrict__ bw, const float* __restrict__ bb,
    float*    __restrict__ ego_out,        // if WRITE_F32
    ushort_t* __restrict__ b16_out,        // if WRITE_B16
    float*    __restrict__ out, int out_col)
{
    __shared__ float s_lds[32][DIM];
    __shared__ float p_lds[32][DIM];

    const int o  = threadIdx.x & 63;   // output dim owned by this lane
    const int wv = threadIdx.x >> 6;   // wave in block

    // per-lane weight registers: w0[k] = gw[o][k], w1[k] = bw[o][k]
    float w0[DIM], w1[DIM];
#pragma unroll
    for (int k4 = 0; k4 < DIM / 4; ++k4) {
        float4 a = *(const float4*)(gw + (size_t)o * DIM + k4 * 4);
        float4 b = *(const float4*)(bw + (size_t)o * DIM + k4 * 4);
        w0[4*k4+0] = a.x; w0[4*k4+1] = a.y; w0[4*k4+2] = a.z; w0[4*k4+3] = a.w;
        w1[4*k4+0] = b.x; w1[4*k4+1] = b.y; w1[4*k4+2] = b.z; w1[4*k4+3] = b.w;
    }
    const float bias = gb[o] + bb[o];

    for (int tile = blockIdx.x * 32; tile < N_NODES; tile += gridDim.x * 32) {
        int nmax = min(32, N_NODES - tile);
        __syncthreads();
        // ---- stage s,p for 32 nodes ----
        const float4* sd4 = (const float4*)side + (size_t)tile * 16;
        float4* s4 = (float4*)&s_lds[0][0];
        float4* p4 = (float4*)&p_lds[0][0];
        if (EGO_B16) {
            const uint4* eb4 = (const uint4*)ego_b16 + (size_t)tile * 8;
            for (int i = threadIdx.x; i < nmax * 8; i += 256) {
                uint4 xb = eb4[i];
                float4 s0 = sd4[2*i], s1 = sd4[2*i+1];
                float e0=blo(xb.x), e1=bhi(xb.x), e2=blo(xb.y), e3=bhi(xb.y);
                float e4=blo(xb.z), e5=bhi(xb.z), e6=blo(xb.w), e7=bhi(xb.w);
                s4[2*i]   = make_float4(s0.x+e0, s0.y+e1, s0.z+e2, s0.w+e3);
                s4[2*i+1] = make_float4(s1.x+e4, s1.y+e5, s1.z+e6, s1.w+e7);
                p4[2*i]   = make_float4(s0.x*e0, s0.y*e1, s0.z*e2, s0.w*e3);
                p4[2*i+1] = make_float4(s1.x*e4, s1.y*e5, s1.z*e6, s1.w*e7);
            }
        } else {
            const float4* eg4 = (const float4*)ego_f32 + (size_t)tile * 16;
            for (int i = threadIdx.x; i < nmax * 16; i += 256) {
                float4 e = eg4[i], s = sd4[i];
                s4[i] = make_float4(s.x+e.x, s.y+e.y, s.z+e.z, s.w+e.w);
                p4[i] = make_float4(s.x*e.x, s.y*e.y, s.z*e.z, s.w*e.w);
            }
        }
        __syncthreads();
        // ---- compute: wave wv handles nodes wv, wv+4, ... ----
        for (int n = wv; n < nmax; n += 4) {
            const float4* srow = (const float4*)&s_lds[n][0];
            const float4* prow = (const float4*)&p_lds[n][0];
            float a0 = bias, a1 = 0.f, a2 = 0.f, a3 = 0.f;
#pragma unroll
            for (int k4 = 0; k4 < 16; ++k4) {
                float4 sk = srow[k4];     // all-lane broadcast reads
                float4 pk = prow[k4];
                a0 = fmaf(sk.x, w0[4*k4+0], a0); a1 = fmaf(pk.x, w1[4*k4+0], a1);
                a2 = fmaf(sk.y, w0[4*k4+1], a2); a3 = fmaf(pk.y, w1[4*k4+1], a3);
                a0 = fmaf(sk.z, w0[4*k4+2], a0); a1 = fmaf(pk.z, w1[4*k4+2], a1);
                a2 = fmaf(sk.w, w0[4*k4+3], a2); a3 = fmaf(pk.w, w1[4*k4+3], a3);
            }
            float acc = (a0 + a1) + (a2 + a3);
            float y = acc > 0.f ? acc : 0.2f * acc;   // leaky_relu(0.2)
            size_t node = (size_t)(tile + n);

            if (WRITE_F32) ego_out[node * DIM + o] = y;
            if (WRITE_B16) b16_out[node * DIM + o] = f2b(y);

            float ss = y * y;
#pragma unroll
            for (int off = 32; off > 0; off >>= 1)
                ss += __shfl_xor(ss, off);
            float inv = 1.0f / fmaxf(sqrtf(ss), 1e-12f);
            out[node * 192 + out_col + o] = y * inv;
        }
    }
}

// out[:, 0:64] = emb
__global__ __launch_bounds__(256) void copy_emb_kernel(
    const float4* __restrict__ emb, float4* __restrict__ out)
{
    int i = blockIdx.x * blockDim.x + threadIdx.x;
    if (i >= N_NODES * 16) return;
    int n = i >> 4, j = i & 15;
    out[(size_t)n * 48 + j] = emb[i];
}

extern "C" void kernel_launch(void* const* d_in, const int* in_sizes, int n_in,
                              void* d_out, int out_size, void* d_ws, size_t ws_size,
                              hipStream_t stream)
{
    const float* emb   = (const float*)d_in[0];
    const float* gc_w0 = (const float*)d_in[1];
    const float* gc_b0 = (const float*)d_in[2];
    const float* bi_w0 = (const float*)d_in[3];
    const float* bi_b0 = (const float*)d_in[4];
    const float* gc_w1 = (const float*)d_in[5];
    const float* gc_b1 = (const float*)d_in[6];
    const float* bi_w1 = (const float*)d_in[7];
    const float* bi_b1 = (const float*)d_in[8];
    const int*   rows  = (const int*)d_in[9];
    const int*   cols  = (const int*)d_in[10];
    const float* vals  = (const float*)d_in[11];
    const int    nnz   = in_sizes[9];

    float* out = (float*)d_out;

    // ---- workspace layout ----
    char* ws = (char*)d_ws;
    size_t off = 0;
    auto alloc = [&](size_t bytes) { char* p = ws + off; off += (bytes + 15) & ~size_t(15); return p; };
    float*    side    = (float*)   alloc((size_t)N_NODES * DIM * sizeof(float));
    int2*     meta    = (int2*)    alloc((size_t)nnz * sizeof(int2));
    ushort_t* ego_b   = (ushort_t*)alloc((size_t)N_NODES * DIM * sizeof(ushort_t)); // emb_b / ego1_b (time-shared)
    int*      counts  = (int*)     alloc((size_t)N_NODES * sizeof(int));
    int*      row_ptr = (int*)     alloc((size_t)(N_NODES + 1) * sizeof(int));
    int*      fill    = (int*)     alloc((size_t)N_NODES * sizeof(int));
    int*      bsum    = (int*)     alloc(1024 * sizeof(int));
    const bool csr_ok = off <= ws_size;

    const int eb   = (nnz + 255) / 256;
    const int nb_s = (N_NODES + SCAN_B - 1) / SCAN_B;
    const int nbN  = (N_NODES + 255) / 256;
    const int spmm_blocks  = (N_NODES * 64 + 255) / 256;
    const int dense_blocks = (N_NODES + 31) / 32;

    if (csr_ok) {
        // ---- CSR build (shared by both layers) ----
        hipMemsetAsync(counts, 0, (size_t)N_NODES * sizeof(int), stream);
        hist_kernel<<<eb, 256, 0, stream>>>(rows, counts, nnz);
        scan1_kernel<<<nb_s, 256, 0, stream>>>(counts, row_ptr, bsum, N_NODES);
        scan2_kernel<<<1, 256, 0, stream>>>(bsum, nb_s);
        scan3_kernel<<<nbN, 256, 0, stream>>>(row_ptr, fill, bsum, N_NODES, nnz);
        scatter_kernel<<<eb, 256, 0, stream>>>(rows, cols, vals, fill, meta, nnz);

        // bf16 gather table of emb
        convert_bf16_kernel<<<(N_NODES * 16 + 255) / 256, 256, 0, stream>>>(
            (const float4*)emb, (ushort4*)ego_b, N_NODES * 16);

        // ---- layer 0 ----
        spmm_csr_b_kernel<<<spmm_blocks, 256, 0, stream>>>(
            (const uint4*)ego_b, row_ptr, meta, side);
        dense_norm_kernel<false, false, true><<<dense_blocks, 256, 0, stream>>>(
            emb, nullptr, side, gc_w0, gc_b0, bi_w0, bi_b0,
            nullptr, ego_b, out, DIM);              // overwrites ego_b with ego1 (bf16)

        // ---- layer 1 ----
        spmm_csr_b_kernel<<<spmm_blocks, 256, 0, stream>>>(
            (const uint4*)ego_b, row_ptr, meta, side);
        dense_norm_kernel<true, false, false><<<dense_blocks, 256, 0, stream>>>(
            nullptr, ego_b, side, gc_w1, gc_b1, bi_w1, bi_b1,
            nullptr, nullptr, out, 2 * DIM);
    } else {
        // ---- fallback: atomic SpMM, fp32 throughout ----
        float* ego1 = (float*)meta;   // reuse
        const size_t side_bytes = (size_t)N_NODES * DIM * sizeof(float);
        const long long total = (long long)nnz * DIM;
        const int ab = (int)((total + 255) / 256);
        hipMemsetAsync(side, 0, side_bytes, stream);
        spmm_atomic_kernel<<<ab, 256, 0, stream>>>(emb, rows, cols, vals, side, nnz);
        dense_norm_kernel<false, true, false><<<dense_blocks, 256, 0, stream>>>(
            emb, nullptr, side, gc_w0, gc_b0, bi_w0, bi_b0,
            ego1, nullptr, out, DIM);
        hipMemsetAsync(side, 0, side_bytes, stream);
        spmm_atomic_kernel<<<ab, 256, 0, stream>>>(ego1, rows, cols, vals, side, nnz);
        dense_norm_kernel<false, false, false><<<dense_blocks, 256, 0, stream>>>(
            ego1, nullptr, side, gc_w1, gc_b1, bi_w1, bi_b1,
            nullptr, nullptr, out, 2 * DIM);
    }

    copy_emb_kernel<<<(N_NODES * 16 + 255) / 256, 256, 0, stream>>>(
        (const float4*)emb, (float4*)out);
}

// Round 5
// 1342.859 us; speedup vs baseline: 3.8182x; 1.4579x over previous
//
#include <hip/hip_runtime.h>

// NGCF forward, MI355X. Sizes fixed by the problem.
constexpr int N_NODES = 300000;   // N_USERS + N_ITEMS
constexpr int DIM = 64;

// Bucketed CSR build parameters
constexpr int CHUNK  = 8192;            // edges per binning block
constexpr int B_ROWS = 256;             // rows per bucket (bucket = row >> 8)
constexpr int NB_B   = (N_NODES + B_ROWS - 1) / B_ROWS;   // 1172 buckets
constexpr int CAP    = 12288;           // max edges/bucket staged in LDS (avg ~8192)
constexpr int SCAN_B = 4096;            // elements per scan1 block (16/thread)

typedef unsigned short ushort_t;
typedef unsigned char  uchar_t;

__device__ __forceinline__ float blo(unsigned u) { return __uint_as_float(u << 16); }
__device__ __forceinline__ float bhi(unsigned u) { return __uint_as_float(u & 0xffff0000u); }
__device__ __forceinline__ ushort_t f2b(float f) {            // fp32 -> bf16 (RNE)
    unsigned u = __float_as_uint(f);
    return (ushort_t)((u + 0x7fffu + ((u >> 16) & 1u)) >> 16);
}

// ---------------------------------------------------------------------------
// k1: per-chunk bucket histogram. histT[chunk][b] (coalesced write).
// ---------------------------------------------------------------------------
__global__ __launch_bounds__(256) void binhist_kernel(
    const int* __restrict__ rows, int* __restrict__ histT, int nnz)
{
    __shared__ int cnt[NB_B];
    for (int i = threadIdx.x; i < NB_B; i += 256) cnt[i] = 0;
    __syncthreads();
    int base = blockIdx.x * CHUNK;
#pragma unroll
    for (int k = 0; k < CHUNK / 256; ++k) {
        int e = base + k * 256 + threadIdx.x;
        if (e < nnz) atomicAdd(&cnt[rows[e] >> 8], 1);
    }
    __syncthreads();
    for (int b = threadIdx.x; b < NB_B; b += 256)
        histT[(size_t)blockIdx.x * NB_B + b] = cnt[b];
}

// 32x32 tiled transpose: in[R][C] -> out[C][R]
__global__ __launch_bounds__(256) void transpose_kernel(
    const int* __restrict__ in, int* __restrict__ out, int R, int C)
{
    __shared__ int tile[32][33];
    int c0 = blockIdx.x * 32, r0 = blockIdx.y * 32;
    int tx = threadIdx.x & 31, ty = threadIdx.x >> 5;
#pragma unroll
    for (int k = 0; k < 4; ++k) {
        int r = r0 + ty + k * 8, c = c0 + tx;
        if (r < R && c < C) tile[ty + k * 8][tx] = in[(size_t)r * C + c];
    }
    __syncthreads();
#pragma unroll
    for (int k = 0; k < 4; ++k) {
        int c = c0 + ty + k * 8, r = r0 + tx;
        if (c < C && r < R) out[(size_t)c * R + r] = tile[tx][ty + k * 8];
    }
}

// ---------------------------------------------------------------------------
// Exclusive scan over n elements (in place): scan1 (per-4096 block) ->
// scan2 (block sums, nb<=2048) -> scan3 (add block offsets).
// ---------------------------------------------------------------------------
__global__ __launch_bounds__(256) void scan1_kernel(
    int* __restrict__ a, int* __restrict__ bsum, int n)
{
    __shared__ int tsum[256];
    int base = blockIdx.x * SCAN_B;
    int v[16];
    int s = 0;
#pragma unroll
    for (int k = 0; k < 16; ++k) {
        int i = base + threadIdx.x * 16 + k;
        v[k] = (i < n) ? a[i] : 0;
        s += v[k];
    }
    tsum[threadIdx.x] = s;
    __syncthreads();
    for (int off = 1; off < 256; off <<= 1) {
        int u = (threadIdx.x >= off) ? tsum[threadIdx.x - off] : 0;
        __syncthreads();
        tsum[threadIdx.x] += u;
        __syncthreads();
    }
    int excl = (threadIdx.x == 0) ? 0 : tsum[threadIdx.x - 1];
#pragma unroll
    for (int k = 0; k < 16; ++k) {
        int i = base + threadIdx.x * 16 + k;
        if (i < n) a[i] = excl;
        excl += v[k];
    }
    if (threadIdx.x == 255) bsum[blockIdx.x] = tsum[255];
}

__global__ __launch_bounds__(256) void scan2_kernel(int* bsum, int nb)   // nb <= 2048
{
    __shared__ int tsum[256];
    int v[8];
    int s = 0;
#pragma unroll
    for (int k = 0; k < 8; ++k) {
        int i = threadIdx.x * 8 + k;
        v[k] = (i < nb) ? bsum[i] : 0;
        s += v[k];
    }
    tsum[threadIdx.x] = s;
    __syncthreads();
    for (int off = 1; off < 256; off <<= 1) {
        int u = (threadIdx.x >= off) ? tsum[threadIdx.x - off] : 0;
        __syncthreads();
        tsum[threadIdx.x] += u;
        __syncthreads();
    }
    int excl = (threadIdx.x == 0) ? 0 : tsum[threadIdx.x - 1];
#pragma unroll
    for (int k = 0; k < 8; ++k) {
        int i = threadIdx.x * 8 + k;
        if (i < nb) bsum[i] = excl;
        excl += v[k];
    }
}

__global__ __launch_bounds__(256) void scan3_kernel(
    int* __restrict__ a, const int* __restrict__ bsum, int n)
{
    int i = blockIdx.x * 256 + threadIdx.x;
    if (i < n) a[i] += bsum[i >> 12];    // SCAN_B = 4096
}

// ---------------------------------------------------------------------------
// k5: binned scatter. curT[chunk][b] = reserved global cursor for this
// (chunk,bucket). Payload lands grouped by bucket (coalesced short runs).
// ---------------------------------------------------------------------------
__global__ __launch_bounds__(256) void binscatter_kernel(
    const int* __restrict__ rows, const int* __restrict__ cols,
    const float* __restrict__ vals, const int* __restrict__ curT,
    int2* __restrict__ staged_cv, uchar_t* __restrict__ staged_lr, int nnz)
{
    __shared__ int cur[NB_B];
    for (int b = threadIdx.x; b < NB_B; b += 256)
        cur[b] = curT[(size_t)blockIdx.x * NB_B + b];
    __syncthreads();
    int base = blockIdx.x * CHUNK;
#pragma unroll
    for (int k = 0; k < CHUNK / 256; ++k) {
        int e = base + k * 256 + threadIdx.x;
        if (e < nnz) {
            int r = rows[e];
            int p = atomicAdd(&cur[r >> 8], 1);
            staged_cv[p] = make_int2(cols[e], __float_as_int(vals[e]));
            staged_lr[p] = (uchar_t)(r & 255);
        }
    }
}

// ---------------------------------------------------------------------------
// k6: per-bucket finalize. Stages the bucket's edges in LDS, builds row_ptr,
// and permutes the payload IN PLACE (staged_cv == meta) into row order.
// Final random writes are confined to a ~64KB L2-resident region.
// ---------------------------------------------------------------------------
__global__ __launch_bounds__(256) void bucketfinal_kernel(
    const int* __restrict__ histS,      // [NB_B][NCH] scanned (bucket-major)
    const uchar_t* __restrict__ staged_lr,
    int2* __restrict__ meta,            // == staged_cv
    int* __restrict__ row_ptr, int nnz, int nch)
{
    __shared__ int2    cv[CAP];
    __shared__ uchar_t lr[CAP];
    __shared__ int cnt[256], scn[256], cur[256];

    int b    = blockIdx.x;
    int base = histS[(size_t)b * nch];
    int end  = (b + 1 < gridDim.x) ? histS[(size_t)(b + 1) * nch] : nnz;
    int n    = min(end - base, CAP);    // CAP never hit for uniform-random rows

    for (int i = threadIdx.x; i < n; i += 256) lr[i] = staged_lr[base + i];
    cnt[threadIdx.x] = 0;
    __syncthreads();
    for (int i = threadIdx.x; i < n; i += 256) atomicAdd(&cnt[lr[i]], 1);
    __syncthreads();
    // inclusive scan of cnt -> excl prefix
    int v = cnt[threadIdx.x];
    scn[threadIdx.x] = v;
    __syncthreads();
    for (int off = 1; off < 256; off <<= 1) {
        int u = (threadIdx.x >= off) ? scn[threadIdx.x - off] : 0;
        __syncthreads();
        scn[threadIdx.x] += u;
        __syncthreads();
    }
    int excl = scn[threadIdx.x] - v;

    int r0 = b * B_ROWS;
    int nr = min(B_ROWS, N_NODES - r0);
    if (threadIdx.x < nr) row_ptr[r0 + threadIdx.x] = base + excl;
    if (b == gridDim.x - 1 && threadIdx.x == 0) row_ptr[N_NODES] = nnz;

    cur[threadIdx.x] = excl;
    for (int i = threadIdx.x; i < n; i += 256) cv[i] = meta[base + i];
    __syncthreads();
    for (int i = threadIdx.x; i < n; i += 256) {
        int d = atomicAdd(&cur[lr[i]], 1);
        meta[base + d] = cv[i];
    }
}

// fp32 [N,64] -> bf16 table [N,64]
__global__ __launch_bounds__(256) void convert_bf16_kernel(
    const float4* __restrict__ src, ushort4* __restrict__ dst, int n4)
{
    int i = blockIdx.x * 256 + threadIdx.x;
    if (i >= n4) return;
    float4 x = src[i];
    ushort4 u;
    u.x = f2b(x.x); u.y = f2b(x.y); u.z = f2b(x.z); u.w = f2b(x.w);
    dst[i] = u;
}

// ---------------------------------------------------------------------------
// CSR SpMM with bf16 gather table: one wave per row, 8 edge slots x 8
// dim-eighths, fp32 accumulate, no atomics.
// ---------------------------------------------------------------------------
__global__ __launch_bounds__(256) void spmm_csr_b_kernel(
    const uint4* __restrict__ ego_b,
    const int*   __restrict__ row_ptr,
    const int2*  __restrict__ meta,
    float*       __restrict__ side)
{
    int wid = (blockIdx.x * 256 + threadIdx.x) >> 6;
    if (wid >= N_NODES) return;
    int lane = threadIdx.x & 63;
    int g = lane >> 3;
    int q = lane & 7;

    int start = row_ptr[wid];
    int end   = row_ptr[wid + 1];

    float acc[8];
#pragma unroll
    for (int i = 0; i < 8; ++i) acc[i] = 0.f;

    for (int j = start + g; j < end; j += 8) {
        int2 m = meta[j];
        float v = __int_as_float(m.y);
        uint4 x = ego_b[(size_t)m.x * 8 + q];
        acc[0] += v * blo(x.x); acc[1] += v * bhi(x.x);
        acc[2] += v * blo(x.y); acc[3] += v * bhi(x.y);
        acc[4] += v * blo(x.z); acc[5] += v * bhi(x.z);
        acc[6] += v * blo(x.w); acc[7] += v * bhi(x.w);
    }
#pragma unroll
    for (int off = 8; off <= 32; off <<= 1) {
#pragma unroll
        for (int i = 0; i < 8; ++i) acc[i] += __shfl_xor(acc[i], off);
    }
    if (g == 0) {
        float4* dst = (float4*)(side + (size_t)wid * DIM + q * 8);
        dst[0] = make_float4(acc[0], acc[1], acc[2], acc[3]);
        dst[1] = make_float4(acc[4], acc[5], acc[6], acc[7]);
    }
}

// Fallback SpMM (atomic, edge-parallel) if ws is too small.
__global__ __launch_bounds__(256) void spmm_atomic_kernel(
    const float* __restrict__ ego,
    const int*   __restrict__ rows,
    const int*   __restrict__ cols,
    const float* __restrict__ vals,
    float*       __restrict__ side,
    int nnz)
{
    long long i = (long long)blockIdx.x * blockDim.x + threadIdx.x;
    long long total = (long long)nnz * DIM;
    if (i >= total) return;
    int e = (int)(i >> 6);
    int d = (int)(i & 63);
    atomicAdd(side + ((size_t)rows[e] * DIM + d), vals[e] * ego[(size_t)cols[e] * DIM + d]);
}

// ---------------------------------------------------------------------------
// Dense part of one NGCF layer (unchanged from round 4).
// ---------------------------------------------------------------------------
template<bool EGO_B16, bool WRITE_F32, bool WRITE_B16>
__global__ __launch_bounds__(256) void dense_norm_kernel(
    const float*   __restrict__ ego_f32,
    const ushort_t* __restrict__ ego_b16,
    const float* __restrict__ side,
    const float* __restrict__ gw, const float* __restrict__ gb,
    const float* __restrict__ bw, const float* __restrict__ bb,
    float*    __restrict__ ego_out,
    ushort_t* __restrict__ b16_out,
    float*    __restrict__ out, int out_col)
{
    __shared__ float s_lds[32][DIM];
    __shared__ float p_lds[32][DIM];

    const int o  = threadIdx.x & 63;
    const int wv = threadIdx.x >> 6;

    float w0[DIM], w1[DIM];
#pragma unroll
    for (int k4 = 0; k4 < DIM / 4; ++k4) {
        float4 a = *(const float4*)(gw + (size_t)o * DIM + k4 * 4);
        float4 b = *(const float4*)(bw + (size_t)o * DIM + k4 * 4);
        w0[4*k4+0] = a.x; w0[4*k4+1] = a.y; w0[4*k4+2] = a.z; w0[4*k4+3] = a.w;
        w1[4*k4+0] = b.x; w1[4*k4+1] = b.y; w1[4*k4+2] = b.z; w1[4*k4+3] = b.w;
    }
    const float bias = gb[o] + bb[o];

    for (int tile = blockIdx.x * 32; tile < N_NODES; tile += gridDim.x * 32) {
        int nmax = min(32, N_NODES - tile);
        __syncthreads();
        const float4* sd4 = (const float4*)side + (size_t)tile * 16;
        float4* s4 = (float4*)&s_lds[0][0];
        float4* p4 = (float4*)&p_lds[0][0];
        if (EGO_B16) {
            const uint4* eb4 = (const uint4*)ego_b16 + (size_t)tile * 8;
            for (int i = threadIdx.x; i < nmax * 8; i += 256) {
                uint4 xb = eb4[i];
                float4 s0 = sd4[2*i], s1 = sd4[2*i+1];
                float e0=blo(xb.x), e1=bhi(xb.x), e2=blo(xb.y), e3=bhi(xb.y);
                float e4=blo(xb.z), e5=bhi(xb.z), e6=blo(xb.w), e7=bhi(xb.w);
                s4[2*i]   = make_float4(s0.x+e0, s0.y+e1, s0.z+e2, s0.w+e3);
                s4[2*i+1] = make_float4(s1.x+e4, s1.y+e5, s1.z+e6, s1.w+e7);
                p4[2*i]   = make_float4(s0.x*e0, s0.y*e1, s0.z*e2, s0.w*e3);
                p4[2*i+1] = make_float4(s1.x*e4, s1.y*e5, s1.z*e6, s1.w*e7);
            }
        } else {
            const float4* eg4 = (const float4*)ego_f32 + (size_t)tile * 16;
            for (int i = threadIdx.x; i < nmax * 16; i += 256) {
                float4 e = eg4[i], s = sd4[i];
                s4[i] = make_float4(s.x+e.x, s.y+e.y, s.z+e.z, s.w+e.w);
                p4[i] = make_float4(s.x*e.x, s.y*e.y, s.z*e.z, s.w*e.w);
            }
        }
        __syncthreads();
        for (int n = wv; n < nmax; n += 4) {
            const float4* srow = (const float4*)&s_lds[n][0];
            const float4* prow = (const float4*)&p_lds[n][0];
            float a0 = bias, a1 = 0.f, a2 = 0.f, a3 = 0.f;
#pragma unroll
            for (int k4 = 0; k4 < 16; ++k4) {
                float4 sk = srow[k4];
                float4 pk = prow[k4];
                a0 = fmaf(sk.x, w0[4*k4+0], a0); a1 = fmaf(pk.x, w1[4*k4+0], a1);
                a2 = fmaf(sk.y, w0[4*k4+1], a2); a3 = fmaf(pk.y, w1[4*k4+1], a3);
                a0 = fmaf(sk.z, w0[4*k4+2], a0); a1 = fmaf(pk.z, w1[4*k4+2], a1);
                a2 = fmaf(sk.w, w0[4*k4+3], a2); a3 = fmaf(pk.w, w1[4*k4+3], a3);
            }
            float acc = (a0 + a1) + (a2 + a3);
            float y = acc > 0.f ? acc : 0.2f * acc;
            size_t node = (size_t)(tile + n);

            if (WRITE_F32) ego_out[node * DIM + o] = y;
            if (WRITE_B16) b16_out[node * DIM + o] = f2b(y);

            float ss = y * y;
#pragma unroll
            for (int off = 32; off > 0; off >>= 1)
                ss += __shfl_xor(ss, off);
            float inv = 1.0f / fmaxf(sqrtf(ss), 1e-12f);
            out[node * 192 + out_col + o] = y * inv;
        }
    }
}

// out[:, 0:64] = emb
__global__ __launch_bounds__(256) void copy_emb_kernel(
    const float4* __restrict__ emb, float4* __restrict__ out)
{
    int i = blockIdx.x * blockDim.x + threadIdx.x;
    if (i >= N_NODES * 16) return;
    int n = i >> 4, j = i & 15;
    out[(size_t)n * 48 + j] = emb[i];
}

extern "C" void kernel_launch(void* const* d_in, const int* in_sizes, int n_in,
                              void* d_out, int out_size, void* d_ws, size_t ws_size,
                              hipStream_t stream)
{
    const float* emb   = (const float*)d_in[0];
    const float* gc_w0 = (const float*)d_in[1];
    const float* gc_b0 = (const float*)d_in[2];
    const float* bi_w0 = (const float*)d_in[3];
    const float* bi_b0 = (const float*)d_in[4];
    const float* gc_w1 = (const float*)d_in[5];
    const float* gc_b1 = (const float*)d_in[6];
    const float* bi_w1 = (const float*)d_in[7];
    const float* bi_b1 = (const float*)d_in[8];
    const int*   rows  = (const int*)d_in[9];
    const int*   cols  = (const int*)d_in[10];
    const float* vals  = (const float*)d_in[11];
    const int    nnz   = in_sizes[9];

    float* out = (float*)d_out;

    const int nch = (nnz + CHUNK - 1) / CHUNK;            // chunks
    const int n2  = NB_B * nch;                           // hist entries
    const size_t hist_bytes = (size_t)n2 * sizeof(int);

    // ---- workspace layout ----
    char* ws = (char*)d_ws;
    size_t off = 0;
    auto alloc = [&](size_t bytes) { char* p = ws + off; off += (bytes + 63) & ~size_t(63); return p; };
    float* side = (float*)alloc((size_t)N_NODES * DIM * sizeof(float));
    int2*  meta = (int2*) alloc((size_t)nnz * sizeof(int2));          // == staged_cv
    // Union region: build-phase {staged_lr, histT, histA}; post-build {ego_b}
    size_t u_build = (((size_t)nnz + 63) & ~size_t(63)) + 2 * ((hist_bytes + 63) & ~size_t(63));
    size_t u_post  = (size_t)N_NODES * DIM * sizeof(ushort_t);
    char*  U = alloc(u_build > u_post ? u_build : u_post);
    uchar_t* staged_lr = (uchar_t*)U;
    int*     histT = (int*)(U + (((size_t)nnz + 63) & ~size_t(63)));
    int*     histA = (int*)((char*)histT + ((hist_bytes + 63) & ~size_t(63)));
    int*     curT  = histT;                               // reuse after transpose 1
    ushort_t* ego_b = (ushort_t*)U;
    int* row_ptr = (int*)alloc((size_t)(N_NODES + 1) * sizeof(int));
    int* bsum    = (int*)alloc(2048 * sizeof(int));
    const bool csr_ok = (off <= ws_size) && (nnz <= 11000000);  // CAP headroom

    const int spmm_blocks  = (N_NODES * 64 + 255) / 256;
    const int dense_blocks = (N_NODES + 31) / 32;

    if (csr_ok) {
        // ---- bucketed CSR build ----
        binhist_kernel<<<nch, 256, 0, stream>>>(rows, histT, nnz);
        {   // histT[nch][NB_B] -> histA[NB_B][nch]
            dim3 g((NB_B + 31) / 32, (nch + 31) / 32);
            transpose_kernel<<<g, 256, 0, stream>>>(histT, histA, nch, NB_B);
        }
        const int nsb = (n2 + SCAN_B - 1) / SCAN_B;       // <= 2048
        scan1_kernel<<<nsb, 256, 0, stream>>>(histA, bsum, n2);
        scan2_kernel<<<1, 256, 0, stream>>>(bsum, nsb);
        scan3_kernel<<<(n2 + 255) / 256, 256, 0, stream>>>(histA, bsum, n2);
        {   // histA[NB_B][nch] (scanned) -> curT[nch][NB_B]
            dim3 g((nch + 31) / 32, (NB_B + 31) / 32);
            transpose_kernel<<<g, 256, 0, stream>>>(histA, curT, NB_B, nch);
        }
        binscatter_kernel<<<nch, 256, 0, stream>>>(rows, cols, vals, curT,
                                                   meta, staged_lr, nnz);
        bucketfinal_kernel<<<NB_B, 256, 0, stream>>>(histA, staged_lr, meta,
                                                     row_ptr, nnz, nch);

        // bf16 gather table of emb (overwrites staged_lr/hist region — now dead)
        convert_bf16_kernel<<<(N_NODES * 16 + 255) / 256, 256, 0, stream>>>(
            (const float4*)emb, (ushort4*)ego_b, N_NODES * 16);

        // ---- layer 0 ----
        spmm_csr_b_kernel<<<spmm_blocks, 256, 0, stream>>>(
            (const uint4*)ego_b, row_ptr, meta, side);
        dense_norm_kernel<false, false, true><<<dense_blocks, 256, 0, stream>>>(
            emb, nullptr, side, gc_w0, gc_b0, bi_w0, bi_b0,
            nullptr, ego_b, out, DIM);

        // ---- layer 1 ----
        spmm_csr_b_kernel<<<spmm_blocks, 256, 0, stream>>>(
            (const uint4*)ego_b, row_ptr, meta, side);
        dense_norm_kernel<true, false, false><<<dense_blocks, 256, 0, stream>>>(
            nullptr, ego_b, side, gc_w1, gc_b1, bi_w1, bi_b1,
            nullptr, nullptr, out, 2 * DIM);
    } else {
        // ---- fallback: atomic SpMM, fp32 throughout ----
        float* ego1 = (float*)meta;
        const size_t side_bytes = (size_t)N_NODES * DIM * sizeof(float);
        const long long total = (long long)nnz * DIM;
        const int ab = (int)((total + 255) / 256);
        hipMemsetAsync(side, 0, side_bytes, stream);
        spmm_atomic_kernel<<<ab, 256, 0, stream>>>(emb, rows, cols, vals, side, nnz);
        dense_norm_kernel<false, true, false><<<dense_blocks, 256, 0, stream>>>(
            emb, nullptr, side, gc_w0, gc_b0, bi_w0, bi_b0,
            ego1, nullptr, out, DIM);
        hipMemsetAsync(side, 0, side_bytes, stream);
        spmm_atomic_kernel<<<ab, 256, 0, stream>>>(ego1, rows, cols, vals, side, nnz);
        dense_norm_kernel<false, false, false><<<dense_blocks, 256, 0, stream>>>(
            ego1, nullptr, side, gc_w1, gc_b1, bi_w1, bi_b1,
            nullptr, nullptr, out, 2 * DIM);
    }

    copy_emb_kernel<<<(N_NODES * 16 + 255) / 256, 256, 0, stream>>>(
        (const float4*)emb, (float4*)out);
}

// Round 6
// 1042.906 us; speedup vs baseline: 4.9163x; 1.2876x over previous
//
#include <hip/hip_runtime.h>

// NGCF forward, MI355X. Sizes fixed by the problem.
constexpr int N_NODES = 300000;   // N_USERS + N_ITEMS
constexpr int DIM = 64;

// Bucketed CSR build parameters
constexpr int CHUNK  = 8192;            // edges per binning block
constexpr int B_ROWS = 256;             // rows per bucket (bucket = row >> 8)
constexpr int NB_B   = (N_NODES + B_ROWS - 1) / B_ROWS;   // 1172 buckets
constexpr int CAP    = 12288;           // max edges/bucket in bucketfinal LDS
constexpr int SCAN_B = 4096;            // elements per scan1 block (16/thread)
constexpr int COL_MASK = (1 << 19) - 1; // col < 2^19 (300000 < 524288)

typedef unsigned short ushort_t;

__device__ __forceinline__ float blo(unsigned u) { return __uint_as_float(u << 16); }
__device__ __forceinline__ float bhi(unsigned u) { return __uint_as_float(u & 0xffff0000u); }
__device__ __forceinline__ ushort_t f2b(float f) {            // fp32 -> bf16 (RNE)
    unsigned u = __float_as_uint(f);
    return (ushort_t)((u + 0x7fffu + ((u >> 16) & 1u)) >> 16);
}

// ---------------------------------------------------------------------------
// k1: per-chunk bucket histogram. histT[chunk][b] (coalesced write).
// ---------------------------------------------------------------------------
__global__ __launch_bounds__(256) void binhist_kernel(
    const int* __restrict__ rows, int* __restrict__ histT, int nnz)
{
    __shared__ int cnt[NB_B];
    for (int i = threadIdx.x; i < NB_B; i += 256) cnt[i] = 0;
    __syncthreads();
    int base = blockIdx.x * CHUNK;
#pragma unroll
    for (int k = 0; k < CHUNK / 256; ++k) {
        int e = base + k * 256 + threadIdx.x;
        if (e < nnz) atomicAdd(&cnt[rows[e] >> 8], 1);
    }
    __syncthreads();
    for (int b = threadIdx.x; b < NB_B; b += 256)
        histT[(size_t)blockIdx.x * NB_B + b] = cnt[b];
}

// 32x32 tiled transpose: in[R][C] -> out[C][R]
__global__ __launch_bounds__(256) void transpose_kernel(
    const int* __restrict__ in, int* __restrict__ out, int R, int C)
{
    __shared__ int tile[32][33];
    int c0 = blockIdx.x * 32, r0 = blockIdx.y * 32;
    int tx = threadIdx.x & 31, ty = threadIdx.x >> 5;
#pragma unroll
    for (int k = 0; k < 4; ++k) {
        int r = r0 + ty + k * 8, c = c0 + tx;
        if (r < R && c < C) tile[ty + k * 8][tx] = in[(size_t)r * C + c];
    }
    __syncthreads();
#pragma unroll
    for (int k = 0; k < 4; ++k) {
        int c = c0 + ty + k * 8, r = r0 + tx;
        if (c < C && r < R) out[(size_t)c * R + r] = tile[tx][ty + k * 8];
    }
}

// ---------------------------------------------------------------------------
// Exclusive scan over n elements (in place).
// ---------------------------------------------------------------------------
__global__ __launch_bounds__(256) void scan1_kernel(
    int* __restrict__ a, int* __restrict__ bsum, int n)
{
    __shared__ int tsum[256];
    int base = blockIdx.x * SCAN_B;
    int v[16];
    int s = 0;
#pragma unroll
    for (int k = 0; k < 16; ++k) {
        int i = base + threadIdx.x * 16 + k;
        v[k] = (i < n) ? a[i] : 0;
        s += v[k];
    }
    tsum[threadIdx.x] = s;
    __syncthreads();
    for (int off = 1; off < 256; off <<= 1) {
        int u = (threadIdx.x >= off) ? tsum[threadIdx.x - off] : 0;
        __syncthreads();
        tsum[threadIdx.x] += u;
        __syncthreads();
    }
    int excl = (threadIdx.x == 0) ? 0 : tsum[threadIdx.x - 1];
#pragma unroll
    for (int k = 0; k < 16; ++k) {
        int i = base + threadIdx.x * 16 + k;
        if (i < n) a[i] = excl;
        excl += v[k];
    }
    if (threadIdx.x == 255) bsum[blockIdx.x] = tsum[255];
}

__global__ __launch_bounds__(256) void scan2_kernel(int* bsum, int nb)   // nb <= 2048
{
    __shared__ int tsum[256];
    int v[8];
    int s = 0;
#pragma unroll
    for (int k = 0; k < 8; ++k) {
        int i = threadIdx.x * 8 + k;
        v[k] = (i < nb) ? bsum[i] : 0;
        s += v[k];
    }
    tsum[threadIdx.x] = s;
    __syncthreads();
    for (int off = 1; off < 256; off <<= 1) {
        int u = (threadIdx.x >= off) ? tsum[threadIdx.x - off] : 0;
        __syncthreads();
        tsum[threadIdx.x] += u;
        __syncthreads();
    }
    int excl = (threadIdx.x == 0) ? 0 : tsum[threadIdx.x - 1];
#pragma unroll
    for (int k = 0; k < 8; ++k) {
        int i = threadIdx.x * 8 + k;
        if (i < nb) bsum[i] = excl;
        excl += v[k];
    }
}

__global__ __launch_bounds__(256) void scan3_kernel(
    int* __restrict__ a, const int* __restrict__ bsum, int n)
{
    int i = blockIdx.x * 256 + threadIdx.x;
    if (i < n) a[i] += bsum[i >> 12];    // SCAN_B = 4096
}

// ---------------------------------------------------------------------------
// k5: binned scatter v2 — LDS counting-sort of the chunk, then ordered flush.
// Payload packed: x = col | (local_row << 19), y = val bits.
// Writes are issued in ascending-destination bursts -> lines close fast.
// ---------------------------------------------------------------------------
__global__ __launch_bounds__(512) void binscatter_kernel(
    const int* __restrict__ rows, const int* __restrict__ cols,
    const float* __restrict__ vals, const int* __restrict__ curT,
    int2* __restrict__ meta, int nnz)
{
    __shared__ int2 cv[CHUNK];      // 64 KB  sorted payload
    __shared__ int  dst[CHUNK];     // 32 KB  global destination per slot
    __shared__ int  cnt[NB_B];      // hist, then per-bucket cursor
    __shared__ int  loc[NB_B];      // local exclusive offsets
    __shared__ int  gb[NB_B];       // global bases for this chunk
    __shared__ int  tsum[512];

    const int tid  = threadIdx.x;
    const int base = blockIdx.x * CHUNK;

    for (int b = tid; b < NB_B; b += 512) cnt[b] = 0;
    __syncthreads();

    // load 16 edges/thread into regs + LDS histogram
    int rb[16], pk[16], vb[16];
#pragma unroll
    for (int k = 0; k < 16; ++k) {
        int e = base + k * 512 + tid;
        if (e < nnz) {
            int r = rows[e];
            rb[k] = r >> 8;
            pk[k] = cols[e] | ((r & 255) << 19);
            vb[k] = __float_as_int(vals[e]);
            atomicAdd(&cnt[rb[k]], 1);
        } else rb[k] = -1;
    }
    __syncthreads();

    // block exclusive scan of cnt[NB_B] (3 contiguous elems per thread)
    int i0 = tid * 3;
    int c0 = 0, c1 = 0, c2 = 0, s = 0;
    if (i0     < NB_B) { c0 = cnt[i0];     s += c0; }
    if (i0 + 1 < NB_B) { c1 = cnt[i0 + 1]; s += c1; }
    if (i0 + 2 < NB_B) { c2 = cnt[i0 + 2]; s += c2; }
    tsum[tid] = s;
    __syncthreads();
    for (int off = 1; off < 512; off <<= 1) {
        int u = (tid >= off) ? tsum[tid - off] : 0;
        __syncthreads();
        tsum[tid] += u;
        __syncthreads();
    }
    int ex = (tid == 0) ? 0 : tsum[tid - 1];
    if (i0     < NB_B) { loc[i0]     = ex; ex += c0; }
    if (i0 + 1 < NB_B) { loc[i0 + 1] = ex; ex += c1; }
    if (i0 + 2 < NB_B) { loc[i0 + 2] = ex; ex += c2; }
    __syncthreads();

    // global bases; reset cursors
    for (int b = tid; b < NB_B; b += 512) {
        gb[b]  = curT[(size_t)blockIdx.x * NB_B + b];
        cnt[b] = 0;
    }
    __syncthreads();

    // place payload into bucket-sorted LDS slots
#pragma unroll
    for (int k = 0; k < 16; ++k) {
        if (rb[k] >= 0) {
            int b   = rb[k];
            int off = atomicAdd(&cnt[b], 1);
            int p   = loc[b] + off;
            cv[p]   = make_int2(pk[k], vb[k]);
            dst[p]  = gb[b] + off;
        }
    }
    __syncthreads();

    // ordered flush: consecutive lanes -> consecutive destinations per run
    int n = min(nnz - base, CHUNK);
    for (int i = tid; i < n; i += 512)
        meta[dst[i]] = cv[i];
}

// ---------------------------------------------------------------------------
// k6: per-bucket finalize. Stages the bucket's edges in LDS, builds row_ptr,
// permutes payload IN PLACE into row order (local row from packed bits).
// ---------------------------------------------------------------------------
__global__ __launch_bounds__(256) void bucketfinal_kernel(
    const int* __restrict__ histS,      // [NB_B][nch] scanned (bucket-major)
    int2* __restrict__ meta,
    int* __restrict__ row_ptr, int nnz, int nch)
{
    __shared__ int2 cv[CAP];            // 96 KB
    __shared__ int cnt[256], scn[256], cur[256];

    int b    = blockIdx.x;
    int base = histS[(size_t)b * nch];
    int end  = (b + 1 < gridDim.x) ? histS[(size_t)(b + 1) * nch] : nnz;
    int n    = min(end - base, CAP);

    cnt[threadIdx.x] = 0;
    __syncthreads();
    for (int i = threadIdx.x; i < n; i += 256) {
        int2 m = meta[base + i];
        cv[i] = m;
        atomicAdd(&cnt[(m.x >> 19) & 255], 1);
    }
    __syncthreads();
    int v = cnt[threadIdx.x];
    scn[threadIdx.x] = v;
    __syncthreads();
    for (int off = 1; off < 256; off <<= 1) {
        int u = (threadIdx.x >= off) ? scn[threadIdx.x - off] : 0;
        __syncthreads();
        scn[threadIdx.x] += u;
        __syncthreads();
    }
    int excl = scn[threadIdx.x] - v;

    int r0 = b * B_ROWS;
    int nr = min(B_ROWS, N_NODES - r0);
    if (threadIdx.x < nr) row_ptr[r0 + threadIdx.x] = base + excl;
    if (b == gridDim.x - 1 && threadIdx.x == 0) row_ptr[N_NODES] = nnz;

    cur[threadIdx.x] = excl;
    __syncthreads();
    for (int i = threadIdx.x; i < n; i += 256) {
        int2 m = cv[i];
        int d = atomicAdd(&cur[(m.x >> 19) & 255], 1);
        meta[base + d] = m;
    }
}

// fp32 [N,64] -> bf16 table [N,64]
__global__ __launch_bounds__(256) void convert_bf16_kernel(
    const float4* __restrict__ src, ushort4* __restrict__ dst, int n4)
{
    int i = blockIdx.x * 256 + threadIdx.x;
    if (i >= n4) return;
    float4 x = src[i];
    ushort4 u;
    u.x = f2b(x.x); u.y = f2b(x.y); u.z = f2b(x.z); u.w = f2b(x.w);
    dst[i] = u;
}

// ---------------------------------------------------------------------------
// CSR SpMM with bf16 gather table: one wave per row, 8 edge slots x 8
// dim-eighths, fp32 accumulate, no atomics. col = meta.x & COL_MASK.
// ---------------------------------------------------------------------------
__global__ __launch_bounds__(256) void spmm_csr_b_kernel(
    const uint4* __restrict__ ego_b,
    const int*   __restrict__ row_ptr,
    const int2*  __restrict__ meta,
    float*       __restrict__ side)
{
    int wid = (blockIdx.x * 256 + threadIdx.x) >> 6;
    if (wid >= N_NODES) return;
    int lane = threadIdx.x & 63;
    int g = lane >> 3;
    int q = lane & 7;

    int start = row_ptr[wid];
    int end   = row_ptr[wid + 1];

    float acc[8];
#pragma unroll
    for (int i = 0; i < 8; ++i) acc[i] = 0.f;

    for (int j = start + g; j < end; j += 8) {
        int2 m = meta[j];
        float v = __int_as_float(m.y);
        uint4 x = ego_b[(size_t)(m.x & COL_MASK) * 8 + q];
        acc[0] += v * blo(x.x); acc[1] += v * bhi(x.x);
        acc[2] += v * blo(x.y); acc[3] += v * bhi(x.y);
        acc[4] += v * blo(x.z); acc[5] += v * bhi(x.z);
        acc[6] += v * blo(x.w); acc[7] += v * bhi(x.w);
    }
#pragma unroll
    for (int off = 8; off <= 32; off <<= 1) {
#pragma unroll
        for (int i = 0; i < 8; ++i) acc[i] += __shfl_xor(acc[i], off);
    }
    if (g == 0) {
        float4* dst = (float4*)(side + (size_t)wid * DIM + q * 8);
        dst[0] = make_float4(acc[0], acc[1], acc[2], acc[3]);
        dst[1] = make_float4(acc[4], acc[5], acc[6], acc[7]);
    }
}

// Fallback SpMM (atomic, edge-parallel) if ws is too small.
__global__ __launch_bounds__(256) void spmm_atomic_kernel(
    const float* __restrict__ ego,
    const int*   __restrict__ rows,
    const int*   __restrict__ cols,
    const float* __restrict__ vals,
    float*       __restrict__ side,
    int nnz)
{
    long long i = (long long)blockIdx.x * blockDim.x + threadIdx.x;
    long long total = (long long)nnz * DIM;
    if (i >= total) return;
    int e = (int)(i >> 6);
    int d = (int)(i & 63);
    atomicAdd(side + ((size_t)rows[e] * DIM + d), vals[e] * ego[(size_t)cols[e] * DIM + d]);
}

// ---------------------------------------------------------------------------
// Dense part of one NGCF layer (unchanged).
// ---------------------------------------------------------------------------
template<bool EGO_B16, bool WRITE_F32, bool WRITE_B16>
__global__ __launch_bounds__(256) void dense_norm_kernel(
    const float*   __restrict__ ego_f32,
    const ushort_t* __restrict__ ego_b16,
    const float* __restrict__ side,
    const float* __restrict__ gw, const float* __restrict__ gb,
    const float* __restrict__ bw, const float* __restrict__ bb,
    float*    __restrict__ ego_out,
    ushort_t* __restrict__ b16_out,
    float*    __restrict__ out, int out_col)
{
    __shared__ float s_lds[32][DIM];
    __shared__ float p_lds[32][DIM];

    const int o  = threadIdx.x & 63;
    const int wv = threadIdx.x >> 6;

    float w0[DIM], w1[DIM];
#pragma unroll
    for (int k4 = 0; k4 < DIM / 4; ++k4) {
        float4 a = *(const float4*)(gw + (size_t)o * DIM + k4 * 4);
        float4 b = *(const float4*)(bw + (size_t)o * DIM + k4 * 4);
        w0[4*k4+0] = a.x; w0[4*k4+1] = a.y; w0[4*k4+2] = a.z; w0[4*k4+3] = a.w;
        w1[4*k4+0] = b.x; w1[4*k4+1] = b.y; w1[4*k4+2] = b.z; w1[4*k4+3] = b.w;
    }
    const float bias = gb[o] + bb[o];

    for (int tile = blockIdx.x * 32; tile < N_NODES; tile += gridDim.x * 32) {
        int nmax = min(32, N_NODES - tile);
        __syncthreads();
        const float4* sd4 = (const float4*)side + (size_t)tile * 16;
        float4* s4 = (float4*)&s_lds[0][0];
        float4* p4 = (float4*)&p_lds[0][0];
        if (EGO_B16) {
            const uint4* eb4 = (const uint4*)ego_b16 + (size_t)tile * 8;
            for (int i = threadIdx.x; i < nmax * 8; i += 256) {
                uint4 xb = eb4[i];
                float4 s0 = sd4[2*i], s1 = sd4[2*i+1];
                float e0=blo(xb.x), e1=bhi(xb.x), e2=blo(xb.y), e3=bhi(xb.y);
                float e4=blo(xb.z), e5=bhi(xb.z), e6=blo(xb.w), e7=bhi(xb.w);
                s4[2*i]   = make_float4(s0.x+e0, s0.y+e1, s0.z+e2, s0.w+e3);
                s4[2*i+1] = make_float4(s1.x+e4, s1.y+e5, s1.z+e6, s1.w+e7);
                p4[2*i]   = make_float4(s0.x*e0, s0.y*e1, s0.z*e2, s0.w*e3);
                p4[2*i+1] = make_float4(s1.x*e4, s1.y*e5, s1.z*e6, s1.w*e7);
            }
        } else {
            const float4* eg4 = (const float4*)ego_f32 + (size_t)tile * 16;
            for (int i = threadIdx.x; i < nmax * 16; i += 256) {
                float4 e = eg4[i], s = sd4[i];
                s4[i] = make_float4(s.x+e.x, s.y+e.y, s.z+e.z, s.w+e.w);
                p4[i] = make_float4(s.x*e.x, s.y*e.y, s.z*e.z, s.w*e.w);
            }
        }
        __syncthreads();
        for (int n = wv; n < nmax; n += 4) {
            const float4* srow = (const float4*)&s_lds[n][0];
            const float4* prow = (const float4*)&p_lds[n][0];
            float a0 = bias, a1 = 0.f, a2 = 0.f, a3 = 0.f;
#pragma unroll
            for (int k4 = 0; k4 < 16; ++k4) {
                float4 sk = srow[k4];
                float4 pk = prow[k4];
                a0 = fmaf(sk.x, w0[4*k4+0], a0); a1 = fmaf(pk.x, w1[4*k4+0], a1);
                a2 = fmaf(sk.y, w0[4*k4+1], a2); a3 = fmaf(pk.y, w1[4*k4+1], a3);
                a0 = fmaf(sk.z, w0[4*k4+2], a0); a1 = fmaf(pk.z, w1[4*k4+2], a1);
                a2 = fmaf(sk.w, w0[4*k4+3], a2); a3 = fmaf(pk.w, w1[4*k4+3], a3);
            }
            float acc = (a0 + a1) + (a2 + a3);
            float y = acc > 0.f ? acc : 0.2f * acc;
            size_t node = (size_t)(tile + n);

            if (WRITE_F32) ego_out[node * DIM + o] = y;
            if (WRITE_B16) b16_out[node * DIM + o] = f2b(y);

            float ss = y * y;
#pragma unroll
            for (int off = 32; off > 0; off >>= 1)
                ss += __shfl_xor(ss, off);
            float inv = 1.0f / fmaxf(sqrtf(ss), 1e-12f);
            out[node * 192 + out_col + o] = y * inv;
        }
    }
}

// out[:, 0:64] = emb
__global__ __launch_bounds__(256) void copy_emb_kernel(
    const float4* __restrict__ emb, float4* __restrict__ out)
{
    int i = blockIdx.x * blockDim.x + threadIdx.x;
    if (i >= N_NODES * 16) return;
    int n = i >> 4, j = i & 15;
    out[(size_t)n * 48 + j] = emb[i];
}

extern "C" void kernel_launch(void* const* d_in, const int* in_sizes, int n_in,
                              void* d_out, int out_size, void* d_ws, size_t ws_size,
                              hipStream_t stream)
{
    const float* emb   = (const float*)d_in[0];
    const float* gc_w0 = (const float*)d_in[1];
    const float* gc_b0 = (const float*)d_in[2];
    const float* bi_w0 = (const float*)d_in[3];
    const float* bi_b0 = (const float*)d_in[4];
    const float* gc_w1 = (const float*)d_in[5];
    const float* gc_b1 = (const float*)d_in[6];
    const float* bi_w1 = (const float*)d_in[7];
    const float* bi_b1 = (const float*)d_in[8];
    const int*   rows  = (const int*)d_in[9];
    const int*   cols  = (const int*)d_in[10];
    const float* vals  = (const float*)d_in[11];
    const int    nnz   = in_sizes[9];

    float* out = (float*)d_out;

    const int nch = (nnz + CHUNK - 1) / CHUNK;            // chunks
    const int n2  = NB_B * nch;                           // hist entries
    const size_t hist_bytes = (size_t)n2 * sizeof(int);

    // ---- workspace layout ----
    char* ws = (char*)d_ws;
    size_t off = 0;
    auto alloc = [&](size_t bytes) { char* p = ws + off; off += (bytes + 63) & ~size_t(63); return p; };
    float* side = (float*)alloc((size_t)N_NODES * DIM * sizeof(float));
    int2*  meta = (int2*) alloc((size_t)nnz * sizeof(int2));
    // Union region: build-phase {histT, histA}; post-build {ego_b}
    size_t u_build = 2 * ((hist_bytes + 63) & ~size_t(63));
    size_t u_post  = (size_t)N_NODES * DIM * sizeof(ushort_t);
    char*  U = alloc(u_build > u_post ? u_build : u_post);
    int*     histT = (int*)U;
    int*     histA = (int*)(U + ((hist_bytes + 63) & ~size_t(63)));
    int*     curT  = histT;                               // reuse after transpose 1
    ushort_t* ego_b = (ushort_t*)U;
    int* row_ptr = (int*)alloc((size_t)(N_NODES + 1) * sizeof(int));
    int* bsum    = (int*)alloc(2048 * sizeof(int));
    const bool csr_ok = (off <= ws_size) && (nnz <= 11000000);  // CAP headroom

    const int spmm_blocks  = (N_NODES * 64 + 255) / 256;
    const int dense_blocks = (N_NODES + 31) / 32;

    if (csr_ok) {
        // ---- bucketed CSR build ----
        binhist_kernel<<<nch, 256, 0, stream>>>(rows, histT, nnz);
        {   // histT[nch][NB_B] -> histA[NB_B][nch]
            dim3 g((NB_B + 31) / 32, (nch + 31) / 32);
            transpose_kernel<<<g, 256, 0, stream>>>(histT, histA, nch, NB_B);
        }
        const int nsb = (n2 + SCAN_B - 1) / SCAN_B;       // <= 2048
        scan1_kernel<<<nsb, 256, 0, stream>>>(histA, bsum, n2);
        scan2_kernel<<<1, 256, 0, stream>>>(bsum, nsb);
        scan3_kernel<<<(n2 + 255) / 256, 256, 0, stream>>>(histA, bsum, n2);
        {   // histA[NB_B][nch] (scanned) -> curT[nch][NB_B]
            dim3 g((nch + 31) / 32, (NB_B + 31) / 32);
            transpose_kernel<<<g, 256, 0, stream>>>(histA, curT, NB_B, nch);
        }
        binscatter_kernel<<<nch, 512, 0, stream>>>(rows, cols, vals, curT, meta, nnz);
        bucketfinal_kernel<<<NB_B, 256, 0, stream>>>(histA, meta, row_ptr, nnz, nch);

        // bf16 gather table of emb (overwrites hist region — now dead)
        convert_bf16_kernel<<<(N_NODES * 16 + 255) / 256, 256, 0, stream>>>(
            (const float4*)emb, (ushort4*)ego_b, N_NODES * 16);

        // ---- layer 0 ----
        spmm_csr_b_kernel<<<spmm_blocks, 256, 0, stream>>>(
            (const uint4*)ego_b, row_ptr, meta, side);
        dense_norm_kernel<false, false, true><<<dense_blocks, 256, 0, stream>>>(
            emb, nullptr, side, gc_w0, gc_b0, bi_w0, bi_b0,
            nullptr, ego_b, out, DIM);

        // ---- layer 1 ----
        spmm_csr_b_kernel<<<spmm_blocks, 256, 0, stream>>>(
            (const uint4*)ego_b, row_ptr, meta, side);
        dense_norm_kernel<true, false, false><<<dense_blocks, 256, 0, stream>>>(
            nullptr, ego_b, side, gc_w1, gc_b1, bi_w1, bi_b1,
            nullptr, nullptr, out, 2 * DIM);
    } else {
        // ---- fallback: atomic SpMM, fp32 throughout ----
        float* ego1 = (float*)meta;
        const size_t side_bytes = (size_t)N_NODES * DIM * sizeof(float);
        const long long total = (long long)nnz * DIM;
        const int ab = (int)((total + 255) / 256);
        hipMemsetAsync(side, 0, side_bytes, stream);
        spmm_atomic_kernel<<<ab, 256, 0, stream>>>(emb, rows, cols, vals, side, nnz);
        dense_norm_kernel<false, true, false><<<dense_blocks, 256, 0, stream>>>(
            emb, nullptr, side, gc_w0, gc_b0, bi_w0, bi_b0,
            ego1, nullptr, out, DIM);
        hipMemsetAsync(side, 0, side_bytes, stream);
        spmm_atomic_kernel<<<ab, 256, 0, stream>>>(ego1, rows, cols, vals, side, nnz);
        dense_norm_kernel<false, false, false><<<dense_blocks, 256, 0, stream>>>(
            ego1, nullptr, side, gc_w1, gc_b1, bi_w1, bi_b1,
            nullptr, nullptr, out, 2 * DIM);
    }

    copy_emb_kernel<<<(N_NODES * 16 + 255) / 256, 256, 0, stream>>>(
        (const float4*)emb, (float4*)out);
}